// Round 1
// baseline (104.316 us; speedup 1.0000x reference)
//
#include <hip/hip_runtime.h>

typedef _Float16 f16x8 __attribute__((ext_vector_type(8)));
typedef float f32x4 __attribute__((ext_vector_type(4)));

static constexpr float kLog2e = 1.44269504088896340736f;

// ws layout (bytes):
//   [0, 65536)        : cfrag  — centers as f16 B-fragments, frag-major
//   [65536, 67584)    : e2[512]  = -beta*log2e * ||c_k||^2
//   [67584, 69632)    : w[512]   = softmax(psi)
//   [69632, 69640)    : sc[2]    = { 2*beta*log2e, -beta*log2e }
#define WS_E2 65536
#define WS_W  (65536 + 2048)
#define WS_SC (65536 + 4096)

__device__ __forceinline__ float fast_exp2(float x) {
#if __has_builtin(__builtin_amdgcn_exp2f)
  return __builtin_amdgcn_exp2f(x);
#else
  return exp2f(x);
#endif
}

// ---------------------------------------------------------------------------
// Pre-kernel 1: softmax(psi) -> w, c2 -> e2, scalars. One block, 512 threads.
// ---------------------------------------------------------------------------
__global__ __launch_bounds__(512) void prep_kernel(
    const float* __restrict__ centers, const float* __restrict__ psi,
    const float* __restrict__ beta, float* __restrict__ e2,
    float* __restrict__ w, float* __restrict__ sc) {
  __shared__ float red[8];
  const int tid = threadIdx.x;      // 0..511 == center index
  const int lane = tid & 63;
  const int wid = tid >> 6;
  const float b = beta[0];
  const float kco = -b * kLog2e;

  // ||c_k||^2 in fp32 (exact path, matches reference c2)
  const float4* crow = (const float4*)(centers + tid * 64);
  float c2 = 0.f;
#pragma unroll
  for (int i = 0; i < 16; ++i) {
    const float4 v = crow[i];
    c2 = fmaf(v.x, v.x, c2); c2 = fmaf(v.y, v.y, c2);
    c2 = fmaf(v.z, v.z, c2); c2 = fmaf(v.w, v.w, c2);
  }

  // softmax over 512 psi values: wave shuffle reduce + 8-wave LDS combine
  const float p = psi[tid];
  float m = p;
#pragma unroll
  for (int d = 1; d < 64; d <<= 1) m = fmaxf(m, __shfl_xor(m, d, 64));
  if (lane == 0) red[wid] = m;
  __syncthreads();
  float mx = red[0];
#pragma unroll
  for (int i = 1; i < 8; ++i) mx = fmaxf(mx, red[i]);
  __syncthreads();
  const float ex = fast_exp2((p - mx) * kLog2e);
  float ssum = ex;
#pragma unroll
  for (int d = 1; d < 64; d <<= 1) ssum += __shfl_xor(ssum, d, 64);
  if (lane == 0) red[wid] = ssum;
  __syncthreads();
  float tot = 0.f;
#pragma unroll
  for (int i = 0; i < 8; ++i) tot += red[i];

  w[tid] = ex / tot;
  e2[tid] = kco * c2;
  if (tid == 0) { sc[0] = 2.f * b * kLog2e; sc[1] = kco; }
}

// ---------------------------------------------------------------------------
// Pre-kernel 2: centers fp32 -> f16 B-fragments, fragment-major so the main
// kernel's B loads are coalesced dwordx4. Layout index:
//   idx = (t*2 + kk)*64 + lane ; lane: n = t*16 + (lane&15), k = kk*32 + (lane>>4)*8 + j
// ---------------------------------------------------------------------------
__global__ __launch_bounds__(64) void cfrag_kernel(
    const float* __restrict__ centers, _Float16* __restrict__ cfrag) {
  const int idx = blockIdx.x * 64 + threadIdx.x;  // [0, 4096)
  const int lane = idx & 63;
  const int pair = idx >> 6;  // t*2 + kk
  const int t = pair >> 1;
  const int kk = pair & 1;
  const int n = t * 16 + (lane & 15);
  const int k = kk * 32 + (lane >> 4) * 8;
  const float* src = centers + n * 64 + k;
  const float4 v0 = *(const float4*)(src);
  const float4 v1 = *(const float4*)(src + 4);
  f16x8 h;
  h[0] = (_Float16)v0.x; h[1] = (_Float16)v0.y;
  h[2] = (_Float16)v0.z; h[3] = (_Float16)v0.w;
  h[4] = (_Float16)v1.x; h[5] = (_Float16)v1.y;
  h[6] = (_Float16)v1.z; h[7] = (_Float16)v1.w;
  *(f16x8*)(cfrag + (size_t)idx * 8) = h;
}

// ---------------------------------------------------------------------------
// Main kernel: 1024 blocks x 256 threads (4 waves). Block owns 128 rows (one
// batch b, since 2048 % 128 == 0). Wave owns 32 rows (2 row-tiles of 16),
// iterates 32 center-tiles of 16: 4x mfma_f32_16x16x32_f16 + fused
// exp2/weighted-sum epilogue. Full block reduce -> one atomicAdd per block.
// ---------------------------------------------------------------------------
__global__ __launch_bounds__(256, 4) void score_kernel(
    const float* __restrict__ F, const _Float16* __restrict__ cfrag,
    const float* __restrict__ e2, const float* __restrict__ wgt,
    const float* __restrict__ sc, float* __restrict__ out) {
  __shared__ float f2s[128];
  __shared__ float wsum[4];
  const int tid = threadIdx.x;
  const int lane = tid & 63;
  const int wv = tid >> 6;    // wave 0..3
  const int quad = lane >> 4; // 0..3
  const int l15 = lane & 15;
  const int R0 = blockIdx.x * 128;

  const float cC = sc[0];   // 2*beta*log2e
  const float kco = sc[1];  // -beta*log2e

  // A fragments (rows direct from global F, fp32->f16 in-reg) + ||f||^2.
  // A layout: m = lane&15, k = kk*32 + quad*8 + j.
  f16x8 a[2][2];
#pragma unroll
  for (int rt = 0; rt < 2; ++rt) {
    const int row = R0 + wv * 32 + rt * 16 + l15;
    const float* fr = F + row * 64 + quad * 8;
    float ssq = 0.f;
#pragma unroll
    for (int kk = 0; kk < 2; ++kk) {
      const float4 v0 = *(const float4*)(fr + kk * 32);
      const float4 v1 = *(const float4*)(fr + kk * 32 + 4);
      a[rt][kk][0] = (_Float16)v0.x; a[rt][kk][1] = (_Float16)v0.y;
      a[rt][kk][2] = (_Float16)v0.z; a[rt][kk][3] = (_Float16)v0.w;
      a[rt][kk][4] = (_Float16)v1.x; a[rt][kk][5] = (_Float16)v1.y;
      a[rt][kk][6] = (_Float16)v1.z; a[rt][kk][7] = (_Float16)v1.w;
      ssq = fmaf(v0.x, v0.x, ssq); ssq = fmaf(v0.y, v0.y, ssq);
      ssq = fmaf(v0.z, v0.z, ssq); ssq = fmaf(v0.w, v0.w, ssq);
      ssq = fmaf(v1.x, v1.x, ssq); ssq = fmaf(v1.y, v1.y, ssq);
      ssq = fmaf(v1.z, v1.z, ssq); ssq = fmaf(v1.w, v1.w, ssq);
    }
    // this lane holds 16 of row (lane&15)'s 64 elems; sum across the 4 quads
    ssq += __shfl_xor(ssq, 16, 64);
    ssq += __shfl_xor(ssq, 32, 64);
    if (quad == 0) f2s[wv * 32 + rt * 16 + l15] = ssq;
  }
  __syncthreads();

  // kco*||f||^2 in C/D layout: row_in_tile = quad*4 + r
  float p0[2][4];
#pragma unroll
  for (int rt = 0; rt < 2; ++rt)
#pragma unroll
    for (int r = 0; r < 4; ++r)
      p0[rt][r] = kco * f2s[wv * 32 + rt * 16 + quad * 4 + r];

  float s = 0.f;
  for (int t = 0; t < 32; ++t) {
    const f16x8 b0 = *(const f16x8*)(cfrag + (size_t)((t * 2 + 0) * 64 + lane) * 8);
    const f16x8 b1 = *(const f16x8*)(cfrag + (size_t)((t * 2 + 1) * 64 + lane) * 8);
    const float e2v = e2[t * 16 + l15];   // col = t*16 + (lane&15)
    const float wv2 = wgt[t * 16 + l15];
    f32x4 acc0 = {0.f, 0.f, 0.f, 0.f};
    f32x4 acc1 = {0.f, 0.f, 0.f, 0.f};
    acc0 = __builtin_amdgcn_mfma_f32_16x16x32_f16(a[0][0], b0, acc0, 0, 0, 0);
    acc0 = __builtin_amdgcn_mfma_f32_16x16x32_f16(a[0][1], b1, acc0, 0, 0, 0);
    acc1 = __builtin_amdgcn_mfma_f32_16x16x32_f16(a[1][0], b0, acc1, 0, 0, 0);
    acc1 = __builtin_amdgcn_mfma_f32_16x16x32_f16(a[1][1], b1, acc1, 0, 0, 0);
    // arg = -beta*log2e*max(f2 + c2 - 2*fc, 0)  ==  min(kf2 + e2 + cC*fc, 0)
    float esum = 0.f;
#pragma unroll
    for (int r = 0; r < 4; ++r) {
      const float arg0 = fminf(fmaf(acc0[r], cC, p0[0][r] + e2v), 0.f);
      const float arg1 = fminf(fmaf(acc1[r], cC, p0[1][r] + e2v), 0.f);
      esum += fast_exp2(arg0);
      esum += fast_exp2(arg1);
    }
    s = fmaf(wv2, esum, s);  // w depends only on col == lane&15: shared by all 8
  }

  // block-wide sum: all lanes hold disjoint (row,col) partials
#pragma unroll
  for (int d = 1; d < 64; d <<= 1) s += __shfl_xor(s, d, 64);
  if (lane == 0) wsum[wv] = s;
  __syncthreads();
  if (tid == 0) {
    const float tot = wsum[0] + wsum[1] + wsum[2] + wsum[3];
    atomicAdd(out + (blockIdx.x >> 4), tot * (1.0f / 2048.0f));
  }
}

extern "C" void kernel_launch(void* const* d_in, const int* in_sizes, int n_in,
                              void* d_out, int out_size, void* d_ws, size_t ws_size,
                              hipStream_t stream) {
  const float* F = (const float*)d_in[0];        // (64, 2048, 64) fp32
  const float* centers = (const float*)d_in[1];  // (512, 64) fp32
  const float* psi = (const float*)d_in[2];      // (512,) fp32
  const float* beta = (const float*)d_in[3];     // scalar fp32
  float* out = (float*)d_out;                    // (64,) fp32
  char* ws = (char*)d_ws;
  _Float16* cfrag = (_Float16*)ws;
  float* e2 = (float*)(ws + WS_E2);
  float* wgt = (float*)(ws + WS_W);
  float* sc = (float*)(ws + WS_SC);

  hipMemsetAsync(out, 0, out_size * sizeof(float), stream);
  prep_kernel<<<1, 512, 0, stream>>>(centers, psi, beta, e2, wgt, sc);
  cfrag_kernel<<<64, 64, 0, stream>>>(centers, cfrag);
  score_kernel<<<1024, 256, 0, stream>>>(F, cfrag, e2, wgt, sc, out);
}